// Round 1
// baseline (340.722 us; speedup 1.0000x reference)
//
#include <hip/hip_runtime.h>

// HybridSymmetricLoss: B=65536, T=3, J=10.
// Per batch b:
//   C[tl][ta] = sum_{jk} BCE(assign[b,ta,jk], labels[b,tl,jk])
//   BCE(p,y) = -(y*clip(log p,-100) + (1-y)*clip(log(1-p),-100))
//            = -(l1 + y*(lp - l1))   with lp,l1 functions of p only
//   loss = min over 6 perms of (1/300) * sum_t C[t][perm[t]]
//   + category BCE permuted by the argmin perm.
// Output scalar = mean_b(loss) + mean_{b,t}(BCE(cat[b,perm[t]], cat_lab[b,t]))

__global__ void zero_out_kernel(float* out) { out[0] = 0.0f; }

__launch_bounds__(256)
__global__ void hybrid_loss_kernel(const float* __restrict__ assign,
                                   const float* __restrict__ cat,
                                   const float* __restrict__ assign_lab,
                                   const float* __restrict__ cat_lab,
                                   float* __restrict__ out,
                                   int B) {
    const int tid  = blockIdx.x * blockDim.x + threadIdx.x;
    const int b    = tid >> 6;            // one wave (64 lanes) per batch element
    const int lane = threadIdx.x & 63;
    if (b >= B) return;

    const float* A = assign     + (size_t)b * 300;  // [t][j*10+k], t-major
    const float* Y = assign_lab + (size_t)b * 300;

    const bool has2 = lane < 36;          // jk = lane+64 < 100

    // lp/l1 per assignment element; d = lp - l1; s1 = sum of l1 per ta-row
    float d[3][2];
    float s1[3];
    #pragma unroll
    for (int t = 0; t < 3; ++t) {
        float p0  = A[t * 100 + lane];
        float lp0 = fmaxf(__logf(p0), -100.0f);
        float l10 = fmaxf(__logf(1.0f - p0), -100.0f);
        d[t][0] = lp0 - l10;
        s1[t]   = l10;
        float d1 = 0.0f;
        if (has2) {
            float p1  = A[t * 100 + lane + 64];
            float lp1 = fmaxf(__logf(p1), -100.0f);
            float l11 = fmaxf(__logf(1.0f - p1), -100.0f);
            d1 = lp1 - l11;
            s1[t] += l11;
        }
        d[t][1] = d1;
    }

    // 9 dot products: dot[tl][ta] = sum_jk y[tl,jk] * d[ta,jk]
    float dot[3][3];
    #pragma unroll
    for (int tl = 0; tl < 3; ++tl) {
        float y0 = Y[tl * 100 + lane];
        float y1 = has2 ? Y[tl * 100 + lane + 64] : 0.0f;
        #pragma unroll
        for (int ta = 0; ta < 3; ++ta) {
            dot[tl][ta] = fmaf(y0, d[ta][0], y1 * d[ta][1]);
        }
    }

    // butterfly wave reduction of the 12 partials (all lanes end with the sum)
    #pragma unroll
    for (int off = 32; off > 0; off >>= 1) {
        #pragma unroll
        for (int t = 0; t < 3; ++t) s1[t] += __shfl_xor(s1[t], off, 64);
        #pragma unroll
        for (int tl = 0; tl < 3; ++tl)
            #pragma unroll
            for (int ta = 0; ta < 3; ++ta)
                dot[tl][ta] += __shfl_xor(dot[tl][ta], off, 64);
    }

    float local = 0.0f;
    if (lane == 0) {
        float C[3][3];
        #pragma unroll
        for (int tl = 0; tl < 3; ++tl)
            #pragma unroll
            for (int ta = 0; ta < 3; ++ta)
                C[tl][ta] = -(s1[ta] + dot[tl][ta]);

        // itertools.permutations(range(3)) order
        const int P[6][3] = {{0,1,2},{0,2,1},{1,0,2},{1,2,0},{2,0,1},{2,1,0}};
        float best = 0.0f; int bi = 0;
        #pragma unroll
        for (int p = 0; p < 6; ++p) {
            float l = C[0][P[p][0]] + C[1][P[p][1]] + C[2][P[p][2]];
            if (p == 0 || l < best) { best = l; bi = p; }
        }

        // category BCE with the winning permutation
        float csum = 0.0f;
        #pragma unroll
        for (int t = 0; t < 3; ++t) {
            float p  = cat[(size_t)b * 3 + P[bi][t]];
            float y  = cat_lab[(size_t)b * 3 + t];
            float lp = fmaxf(__logf(p), -100.0f);
            float l1 = fmaxf(__logf(1.0f - p), -100.0f);
            csum += -(y * lp + (1.0f - y) * l1);
        }

        const float invB = 1.0f / (float)B;
        local = best * (1.0f / 300.0f) * invB + csum * invB * (1.0f / 3.0f);
    }

    // block reduce (4 waves) -> one atomic per block
    __shared__ float sred[4];
    const int w = threadIdx.x >> 6;
    if (lane == 0) sred[w] = local;
    __syncthreads();
    if (threadIdx.x == 0) {
        atomicAdd(out, sred[0] + sred[1] + sred[2] + sred[3]);
    }
}

extern "C" void kernel_launch(void* const* d_in, const int* in_sizes, int n_in,
                              void* d_out, int out_size, void* d_ws, size_t ws_size,
                              hipStream_t stream) {
    const float* assign     = (const float*)d_in[0];
    const float* cat        = (const float*)d_in[1];
    const float* assign_lab = (const float*)d_in[2];
    const float* cat_lab    = (const float*)d_in[3];
    float* out = (float*)d_out;

    const int B = in_sizes[0] / 300;  // T*J*J = 300

    zero_out_kernel<<<1, 1, 0, stream>>>(out);

    // one wave per b; 4 waves (4 b's) per 256-thread block
    const int blocks = (B + 3) / 4;
    hybrid_loss_kernel<<<blocks, 256, 0, stream>>>(assign, cat, assign_lab,
                                                   cat_lab, out, B);
}

// Round 2
// 179.115 us; speedup vs baseline: 1.9022x; 1.9022x over previous
//
#include <hip/hip_runtime.h>

// HybridSymmetricLoss: B=65536, T=3, J=10 (fp32).
// Per batch b: C[tl][ta] = sum_jk BCE(assign[b,ta,jk], labels[b,tl,jk])
//   BCE(p,y) = -(l1 + y*(lp-l1)), lp=clip(log p,-100), l1=clip(log(1-p),-100)
// loss = min over 6 perms of mean_t,jk C[t][perm[t]]  + category BCE under
// the argmin perm.  All logs computed in log2 space (clip at -100/ln2),
// scaled by ln2 once at the end — argmin is scale-invariant.
//
// Mapping: one b per 32-lane half-wave; lanes 0..24 hold 4 contiguous jk
// each (float4 per row).  6 global_load_dwordx4 per wave cover 2 b's.
// 5-stage butterfly (xor 1,2,4,8,16) reduces 12 partials within each half.
// Two-pass sum via d_ws (no same-address atomics).

#define CLIP2 (-144.26950408889634f)   // -100 / ln(2)
#define LN2   (0.6931471805599453f)

__launch_bounds__(256)
__global__ void hybrid_pass1(const float* __restrict__ assign,
                             const float* __restrict__ cat,
                             const float* __restrict__ assign_lab,
                             const float* __restrict__ cat_lab,
                             float* __restrict__ ws, int B) {
    const int lane = threadIdx.x & 63;
    const int sub  = lane & 31;                     // lane within half-wave
    const int b    = (blockIdx.x * blockDim.x + threadIdx.x) >> 5;
    if (b >= B) return;

    const bool act = sub < 25;                      // 25 lanes * 4 = 100 jk
    const float* Ab = assign     + (size_t)b * 300;
    const float* Yb = assign_lab + (size_t)b * 300;

    float s1[3]     = {0.f, 0.f, 0.f};
    float dot[3][3] = {{0.f,0.f,0.f},{0.f,0.f,0.f},{0.f,0.f,0.f}};

    if (act) {
        const int o = sub * 4;
        float4 av0 = *(const float4*)(Ab + o);
        float4 av1 = *(const float4*)(Ab + 100 + o);
        float4 av2 = *(const float4*)(Ab + 200 + o);
        float4 yv0 = *(const float4*)(Yb + o);
        float4 yv1 = *(const float4*)(Yb + 100 + o);
        float4 yv2 = *(const float4*)(Yb + 200 + o);

        float a[3][4] = {{av0.x,av0.y,av0.z,av0.w},
                         {av1.x,av1.y,av1.z,av1.w},
                         {av2.x,av2.y,av2.z,av2.w}};
        float y[3][4] = {{yv0.x,yv0.y,yv0.z,yv0.w},
                         {yv1.x,yv1.y,yv1.z,yv1.w},
                         {yv2.x,yv2.y,yv2.z,yv2.w}};

        float d[3][4];
        #pragma unroll
        for (int t = 0; t < 3; ++t) {
            #pragma unroll
            for (int c = 0; c < 4; ++c) {
                float lp = fmaxf(__log2f(a[t][c]),        CLIP2);
                float l1 = fmaxf(__log2f(1.0f - a[t][c]), CLIP2);
                d[t][c] = lp - l1;
                s1[t]  += l1;
            }
        }
        #pragma unroll
        for (int tl = 0; tl < 3; ++tl) {
            #pragma unroll
            for (int ta = 0; ta < 3; ++ta) {
                float acc = 0.f;
                #pragma unroll
                for (int c = 0; c < 4; ++c)
                    acc = fmaf(y[tl][c], d[ta][c], acc);
                dot[tl][ta] = acc;
            }
        }
    }

    // prefetch category data early so its latency overlaps the butterfly
    float c0=0.f,c1=0.f,c2=0.f,g0=0.f,g1=0.f,g2=0.f;
    if (sub == 0) {
        const float* cb = cat     + (size_t)b * 3;
        const float* gb = cat_lab + (size_t)b * 3;
        c0 = cb[0]; c1 = cb[1]; c2 = cb[2];
        g0 = gb[0]; g1 = gb[1]; g2 = gb[2];
    }

    // 5-stage butterfly within each 32-lane half (covers both b's per wave)
    #pragma unroll
    for (int off = 16; off > 0; off >>= 1) {
        #pragma unroll
        for (int t = 0; t < 3; ++t) s1[t] += __shfl_xor(s1[t], off, 64);
        #pragma unroll
        for (int tl = 0; tl < 3; ++tl)
            #pragma unroll
            for (int ta = 0; ta < 3; ++ta)
                dot[tl][ta] += __shfl_xor(dot[tl][ta], off, 64);
    }

    float local = 0.0f;
    if (sub == 0) {
        float Cm[3][3];
        #pragma unroll
        for (int tl = 0; tl < 3; ++tl)
            #pragma unroll
            for (int ta = 0; ta < 3; ++ta)
                Cm[tl][ta] = -(s1[ta] + dot[tl][ta]);

        // itertools.permutations(range(3)) order; track winning indices
        const int P0[6] = {0,0,1,1,2,2};
        const int P1[6] = {1,2,0,2,0,1};
        const int P2[6] = {2,1,2,0,1,0};
        float best = Cm[0][0] + Cm[1][1] + Cm[2][2];
        int bp0 = 0, bp1 = 1, bp2 = 2;
        #pragma unroll
        for (int p = 1; p < 6; ++p) {
            float l = Cm[0][P0[p]] + Cm[1][P1[p]] + Cm[2][P2[p]];
            if (l < best) { best = l; bp0 = P0[p]; bp1 = P1[p]; bp2 = P2[p]; }
        }

        // category BCE (log2 space) with the winning permutation
        float lp0 = fmaxf(__log2f(c0), CLIP2), l10 = fmaxf(__log2f(1.f-c0), CLIP2);
        float lp1 = fmaxf(__log2f(c1), CLIP2), l11 = fmaxf(__log2f(1.f-c1), CLIP2);
        float lp2 = fmaxf(__log2f(c2), CLIP2), l12 = fmaxf(__log2f(1.f-c2), CLIP2);

        float lpa = (bp0==0)?lp0:((bp0==1)?lp1:lp2);
        float l1a = (bp0==0)?l10:((bp0==1)?l11:l12);
        float lpb = (bp1==0)?lp0:((bp1==1)?lp1:lp2);
        float l1b = (bp1==0)?l10:((bp1==1)?l11:l12);
        float lpc = (bp2==0)?lp0:((bp2==1)?lp1:lp2);
        float l1c = (bp2==0)?l10:((bp2==1)?l11:l12);

        float csum = -(g0*lpa + (1.f-g0)*l1a
                     + g1*lpb + (1.f-g1)*l1b
                     + g2*lpc + (1.f-g2)*l1c);

        local = (best * (1.f/300.f) + csum * (1.f/3.f)) * (LN2 / 65536.f);
    }

    // block reduce: 8 half-wave leaders per 256-thread block
    __shared__ float sred[8];
    if (sub == 0) sred[threadIdx.x >> 5] = local;
    __syncthreads();
    if (threadIdx.x == 0) {
        float s = 0.f;
        #pragma unroll
        for (int i = 0; i < 8; ++i) s += sred[i];
        ws[blockIdx.x] = s;
    }
}

__launch_bounds__(1024)
__global__ void hybrid_pass2(const float* __restrict__ ws,
                             float* __restrict__ out, int n) {
    float s = 0.f;
    for (int i = threadIdx.x; i < n; i += 1024) s += ws[i];
    #pragma unroll
    for (int off = 32; off > 0; off >>= 1) s += __shfl_xor(s, off, 64);
    __shared__ float sm[16];
    if ((threadIdx.x & 63) == 0) sm[threadIdx.x >> 6] = s;
    __syncthreads();
    if (threadIdx.x == 0) {
        float t = 0.f;
        #pragma unroll
        for (int i = 0; i < 16; ++i) t += sm[i];
        out[0] = t;
    }
}

extern "C" void kernel_launch(void* const* d_in, const int* in_sizes, int n_in,
                              void* d_out, int out_size, void* d_ws, size_t ws_size,
                              hipStream_t stream) {
    const float* assign     = (const float*)d_in[0];
    const float* cat        = (const float*)d_in[1];
    const float* assign_lab = (const float*)d_in[2];
    const float* cat_lab    = (const float*)d_in[3];
    float* out = (float*)d_out;
    float* ws  = (float*)d_ws;

    const int B = in_sizes[0] / 300;       // T*J*J = 300
    const int threads = 256;
    const int blocks  = (B * 32 + threads - 1) / threads;   // 32 lanes per b

    hybrid_pass1<<<blocks, threads, 0, stream>>>(assign, cat, assign_lab,
                                                 cat_lab, ws, B);
    hybrid_pass2<<<1, 1024, 0, stream>>>(ws, out, blocks);
}